// Round 4
// baseline (46.703 us; speedup 1.0000x reference)
//
#include <hip/hip_runtime.h>

#define NPOSE  262144
#define NCHAIN (NPOSE * 2)     // two independent FK chains per pose
#define BLOCK  64              // single-wave blocks
#define CPB    64              // chains per block
#define NBLK   (NCHAIN / CPB)  // 8192

// FK translation for one chain given its 36 floats as 9 float4 (row-major 3x3
// matrices, 4 of them). translation = t0 + R0*(t1 + R1*(t2 + R2*t3)),
// R = [cross(c0,c1) | c0 | c1] (columns), t = c2.
__device__ __forceinline__ void chain_translation4(const float4 q[9], float out[3]) {
    float p[36];
#pragma unroll
    for (int j = 0; j < 9; ++j) {
        p[4 * j + 0] = q[j].x; p[4 * j + 1] = q[j].y;
        p[4 * j + 2] = q[j].z; p[4 * j + 3] = q[j].w;
    }
    float v0 = p[27 + 2], v1 = p[27 + 5], v2 = p[27 + 8];  // t3
#pragma unroll
    for (int j = 2; j >= 0; --j) {
        const float* m = p + j * 9;
        const float c00 = m[0], c01 = m[3], c02 = m[6];   // col0
        const float c10 = m[1], c11 = m[4], c12 = m[7];   // col1
        const float t0  = m[2], t1  = m[5], t2  = m[8];   // col2 = translation
        const float x0 = c01 * c12 - c02 * c11;
        const float x1 = c02 * c10 - c00 * c12;
        const float x2 = c00 * c11 - c01 * c10;
        const float w0 = t0 + x0 * v0 + c00 * v1 + c10 * v2;
        const float w1 = t1 + x1 * v0 + c01 * v1 + c11 * v2;
        const float w2 = t2 + x2 * v0 + c02 * v1 + c12 * v2;
        v0 = w0; v1 = w1; v2 = w2;
    }
    out[0] = v0; out[1] = v1; out[2] = v2;
}

__global__ __launch_bounds__(BLOCK, 4) void fk_loss_kernel(const float* __restrict__ outp,
                                                           const float* __restrict__ gtp,
                                                           float* __restrict__ partials) {
    // Linear float4 LDS: rows of 9 float4 (144B) per chain, 16B-aligned.
    // Writes lds4[t+64i] and reads lds4[9t+j] are both bank-uniform (see notes).
    __shared__ float4 lds4[CPB * 9];       // 9216 B -> 16 blocks/CU
    const int t = threadIdx.x;
    const size_t base4 = (size_t)blockIdx.x * (CPB * 9);
    const float4* __restrict__ ga = reinterpret_cast<const float4*>(outp) + base4;
    const float4* __restrict__ gb = reinterpret_cast<const float4*>(gtp) + base4;

    // Coalesced global loads for both inputs (independent, can overlap).
    float4 va[9], vb[9];
#pragma unroll
    for (int i = 0; i < 9; ++i) va[i] = ga[t + 64 * i];
#pragma unroll
    for (int i = 0; i < 9; ++i) vb[i] = gb[t + 64 * i];

    // Stage A (conflict-free ds_write_b128), transpose-read own chain, FK.
#pragma unroll
    for (int i = 0; i < 9; ++i) lds4[t + 64 * i] = va[i];
    __syncthreads();
    float4 ra[9];
#pragma unroll
    for (int j = 0; j < 9; ++j) ra[j] = lds4[t * 9 + j];
    float ta[3];
    chain_translation4(ra, ta);

    // Stage B into the same buffer. Same-wave DS pipe is in-order, so the
    // A-reads above complete before these writes commit; no barrier needed
    // between them. Barrier after writes orders writes vs. the B-reads.
#pragma unroll
    for (int i = 0; i < 9; ++i) lds4[t + 64 * i] = vb[i];
    __syncthreads();
    float4 rb[9];
#pragma unroll
    for (int j = 0; j < 9; ++j) rb[j] = lds4[t * 9 + j];
    float tg[3];
    chain_translation4(rb, tg);

    float acc = 0.0f;
#pragma unroll
    for (int r = 0; r < 3; ++r) { const float d = ta[r] - tg[r]; acc += d * d; }

    // single-wave reduction
#pragma unroll
    for (int off = 32; off > 0; off >>= 1)
        acc += __shfl_down(acc, off, 64);
    if (t == 0) partials[blockIdx.x] = acc;
}

__global__ __launch_bounds__(512) void reduce_kernel(const float* __restrict__ partials,
                                                     float* __restrict__ out) {
    const int t = threadIdx.x;
    const float4* __restrict__ p4 = reinterpret_cast<const float4*>(partials); // 2048 float4
    float s = 0.0f;
#pragma unroll
    for (int i = 0; i < 4; ++i) {
        const float4 v = p4[t + 512 * i];
        s += v.x + v.y + v.z + v.w;
    }
#pragma unroll
    for (int off = 32; off > 0; off >>= 1)
        s += __shfl_down(s, off, 64);
    __shared__ float smem[8];
    const int lane = t & 63, wid = t >> 6;
    if (lane == 0) smem[wid] = s;
    __syncthreads();
    if (t == 0) {
        float tot = 0.0f;
#pragma unroll
        for (int w = 0; w < 8; ++w) tot += smem[w];
        const float mean = tot / (262144.0f * 6.0f);
        out[0] = mean;  // pos_loss
        out[1] = mean;  // vel_loss == pos_loss (gt_prev cancels algebraically)
    }
}

extern "C" void kernel_launch(void* const* d_in, const int* in_sizes, int n_in,
                              void* d_out, int out_size, void* d_ws, size_t ws_size,
                              hipStream_t stream) {
    const float* output_pose = (const float*)d_in[0];
    const float* gt_pose     = (const float*)d_in[1];
    // d_in[2] (gt_prev_pose) cancels algebraically: vel_loss == pos_loss.
    float* out = (float*)d_out;
    float* partials = (float*)d_ws;   // 8192 floats = 32 KB

    fk_loss_kernel<<<NBLK, BLOCK, 0, stream>>>(output_pose, gt_pose, partials);
    reduce_kernel<<<1, 512, 0, stream>>>(partials, out);
}

// Round 5
// 46.336 us; speedup vs baseline: 1.0079x; 1.0079x over previous
//
#include <hip/hip_runtime.h>

#define NPOSE  262144
#define NCHAIN (NPOSE * 2)     // two independent FK chains per pose
#define BLOCK  64              // single-wave blocks
#define CPB    64              // chains per block
#define NBLK   (NCHAIN / CPB)  // 8192

// One FK step: given 3x3 row-major matrix elements e0..e8,
// cols c0=(e0,e3,e6), c1=(e1,e4,e7), t=(e2,e5,e8), R=[cross(c0,c1)|c0|c1]:
// v <- t + R*v
__device__ __forceinline__ void fk_step(float e0, float e1, float e2,
                                        float e3, float e4, float e5,
                                        float e6, float e7, float e8,
                                        float& v0, float& v1, float& v2) {
    const float x0 = e3 * e7 - e6 * e4;
    const float x1 = e6 * e1 - e0 * e7;
    const float x2 = e0 * e4 - e3 * e1;
    const float w0 = e2 + x0 * v0 + e0 * v1 + e1 * v2;
    const float w1 = e5 + x1 * v0 + e3 * v1 + e4 * v2;
    const float w2 = e8 + x2 * v0 + e6 * v1 + e7 * v2;
    v0 = w0; v1 = w1; v2 = w2;
}

// Chain of 4 matrices packed as 9 float4 (36 consecutive floats).
// translation = t0 + R0*(t1 + R1*(t2 + R2*t3)). NO local float arrays /
// pointers into aggregates -> everything stays in VGPRs.
__device__ __forceinline__ void chain_translation_q(
        float4 q0, float4 q1, float4 q2, float4 q3, float4 q4,
        float4 q5, float4 q6, float4 q7, float4 q8,
        float& v0, float& v1, float& v2) {
    v0 = q7.y; v1 = q8.x; v2 = q8.w;                       // t3 = (p29,p32,p35)
    fk_step(q4.z, q4.w, q5.x, q5.y, q5.z, q5.w, q6.x, q6.y, q6.z, v0, v1, v2);  // m2
    fk_step(q2.y, q2.z, q2.w, q3.x, q3.y, q3.z, q3.w, q4.x, q4.y, v0, v1, v2);  // m1
    fk_step(q0.x, q0.y, q0.z, q0.w, q1.x, q1.y, q1.z, q1.w, q2.x, v0, v1, v2);  // m0
}

__global__ __launch_bounds__(BLOCK, 4) void fk_loss_kernel(const float* __restrict__ outp,
                                                           const float* __restrict__ gtp,
                                                           float* __restrict__ partials) {
    // Linear float4 LDS: rows of 9 float4 (144B) per chain, 16B-aligned.
    // Writes lds4[t+64i] and reads lds4[9t+j] are bank-uniform b128 ops.
    __shared__ float4 lds4[CPB * 9];       // 9216 B -> 16 blocks/CU
    const int t = threadIdx.x;
    const size_t base4 = (size_t)blockIdx.x * (CPB * 9);
    const float4* __restrict__ ga = reinterpret_cast<const float4*>(outp) + base4;
    const float4* __restrict__ gb = reinterpret_cast<const float4*>(gtp) + base4;

    // A: coalesced loads, stage to LDS.
    float4 va[9];
#pragma unroll
    for (int i = 0; i < 9; ++i) va[i] = ga[t + 64 * i];
#pragma unroll
    for (int i = 0; i < 9; ++i) lds4[t + 64 * i] = va[i];

    // Issue B loads now; latency hides under barrier + FK-A.
    float4 vb[9];
#pragma unroll
    for (int i = 0; i < 9; ++i) vb[i] = gb[t + 64 * i];

    __syncthreads();
    float4 r0 = lds4[t * 9 + 0], r1 = lds4[t * 9 + 1], r2 = lds4[t * 9 + 2],
           r3 = lds4[t * 9 + 3], r4 = lds4[t * 9 + 4], r5 = lds4[t * 9 + 5],
           r6 = lds4[t * 9 + 6], r7 = lds4[t * 9 + 7], r8 = lds4[t * 9 + 8];
    float tax, tay, taz;
    chain_translation_q(r0, r1, r2, r3, r4, r5, r6, r7, r8, tax, tay, taz);
    __syncthreads();   // all lanes done reading A (1-wave block: near-free)

    // B: stage, read, FK.
#pragma unroll
    for (int i = 0; i < 9; ++i) lds4[t + 64 * i] = vb[i];
    __syncthreads();
    float4 s0 = lds4[t * 9 + 0], s1 = lds4[t * 9 + 1], s2 = lds4[t * 9 + 2],
           s3 = lds4[t * 9 + 3], s4 = lds4[t * 9 + 4], s5 = lds4[t * 9 + 5],
           s6 = lds4[t * 9 + 6], s7 = lds4[t * 9 + 7], s8 = lds4[t * 9 + 8];
    float tgx, tgy, tgz;
    chain_translation_q(s0, s1, s2, s3, s4, s5, s6, s7, s8, tgx, tgy, tgz);

    const float d0 = tax - tgx, d1 = tay - tgy, d2 = taz - tgz;
    float acc = d0 * d0 + d1 * d1 + d2 * d2;

    // single-wave reduction
#pragma unroll
    for (int off = 32; off > 0; off >>= 1)
        acc += __shfl_down(acc, off, 64);
    if (t == 0) partials[blockIdx.x] = acc;
}

__global__ __launch_bounds__(512) void reduce_kernel(const float* __restrict__ partials,
                                                     float* __restrict__ out) {
    const int t = threadIdx.x;
    const float4* __restrict__ p4 = reinterpret_cast<const float4*>(partials); // 2048 float4
    float s = 0.0f;
#pragma unroll
    for (int i = 0; i < 4; ++i) {
        const float4 v = p4[t + 512 * i];
        s += v.x + v.y + v.z + v.w;
    }
#pragma unroll
    for (int off = 32; off > 0; off >>= 1)
        s += __shfl_down(s, off, 64);
    __shared__ float smem[8];
    const int lane = t & 63, wid = t >> 6;
    if (lane == 0) smem[wid] = s;
    __syncthreads();
    if (t == 0) {
        float tot = 0.0f;
#pragma unroll
        for (int w = 0; w < 8; ++w) tot += smem[w];
        const float mean = tot / (262144.0f * 6.0f);
        out[0] = mean;  // pos_loss
        out[1] = mean;  // vel_loss == pos_loss (gt_prev cancels algebraically)
    }
}

extern "C" void kernel_launch(void* const* d_in, const int* in_sizes, int n_in,
                              void* d_out, int out_size, void* d_ws, size_t ws_size,
                              hipStream_t stream) {
    const float* output_pose = (const float*)d_in[0];
    const float* gt_pose     = (const float*)d_in[1];
    // d_in[2] (gt_prev_pose) cancels algebraically: vel_loss == pos_loss.
    float* out = (float*)d_out;
    float* partials = (float*)d_ws;   // 8192 floats = 32 KB

    fk_loss_kernel<<<NBLK, BLOCK, 0, stream>>>(output_pose, gt_pose, partials);
    reduce_kernel<<<1, 512, 0, stream>>>(partials, out);
}

// Round 6
// 28.881 us; speedup vs baseline: 1.6171x; 1.6044x over previous
//
#include <hip/hip_runtime.h>

#define NPOSE  262144
#define NCHAIN (NPOSE * 2)     // two independent FK chains per pose
#define BLOCK  64              // single-wave blocks
#define CPB    64              // chains per block
#define NBLK   (NCHAIN / CPB)  // 8192

typedef __attribute__((address_space(1))) void glb_void_t;
typedef __attribute__((address_space(3))) void lds_void_t;

// One FK step: 3x3 row-major elements e0..e8, cols c0=(e0,e3,e6),
// c1=(e1,e4,e7), t=(e2,e5,e8), R=[cross(c0,c1)|c0|c1]: v <- t + R*v
__device__ __forceinline__ void fk_step(float e0, float e1, float e2,
                                        float e3, float e4, float e5,
                                        float e6, float e7, float e8,
                                        float& v0, float& v1, float& v2) {
    const float x0 = e3 * e7 - e6 * e4;
    const float x1 = e6 * e1 - e0 * e7;
    const float x2 = e0 * e4 - e3 * e1;
    const float w0 = e2 + x0 * v0 + e0 * v1 + e1 * v2;
    const float w1 = e5 + x1 * v0 + e3 * v1 + e4 * v2;
    const float w2 = e8 + x2 * v0 + e6 * v1 + e7 * v2;
    v0 = w0; v1 = w1; v2 = w2;
}

// Chain of 4 matrices packed as 9 float4. translation = t0+R0*(t1+R1*(t2+R2*t3)).
// All by-value scalars: no local arrays, no pointers into aggregates.
__device__ __forceinline__ void chain_translation_q(
        float4 q0, float4 q1, float4 q2, float4 q3, float4 q4,
        float4 q5, float4 q6, float4 q7, float4 q8,
        float& v0, float& v1, float& v2) {
    v0 = q7.y; v1 = q8.x; v2 = q8.w;                       // t3 = (p29,p32,p35)
    fk_step(q4.z, q4.w, q5.x, q5.y, q5.z, q5.w, q6.x, q6.y, q6.z, v0, v1, v2);  // m2
    fk_step(q2.y, q2.z, q2.w, q3.x, q3.y, q3.z, q3.w, q4.x, q4.y, v0, v1, v2);  // m1
    fk_step(q0.x, q0.y, q0.z, q0.w, q1.x, q1.y, q1.z, q1.w, q2.x, v0, v1, v2);  // m0
}

__global__ __launch_bounds__(BLOCK) void fk_loss_kernel(const float* __restrict__ outp,
                                                        const float* __restrict__ gtp,
                                                        float* __restrict__ partials) {
    // Two linear float4 LDS buffers; rows of 9 float4 (144B) per chain.
    // global_load_lds: LDS dest = uniform base + lane*16 -> ldsX[i*64 + lane];
    // global src per-lane contiguous -> perfectly coalesced. Zero VGPRs staged.
    __shared__ float4 ldsA[CPB * 9];       // 9216 B
    __shared__ float4 ldsB[CPB * 9];       // 9216 B  (total 18432 -> 8 blocks/CU)
    const int t = threadIdx.x;
    const size_t base4 = (size_t)blockIdx.x * (CPB * 9);
    const float4* __restrict__ ga = reinterpret_cast<const float4*>(outp) + base4;
    const float4* __restrict__ gb = reinterpret_cast<const float4*>(gtp) + base4;

#pragma unroll
    for (int i = 0; i < 9; ++i)
        __builtin_amdgcn_global_load_lds((glb_void_t*)(ga + t + 64 * i),
                                         (lds_void_t*)(&ldsA[i * 64]), 16, 0, 0);
#pragma unroll
    for (int i = 0; i < 9; ++i)
        __builtin_amdgcn_global_load_lds((glb_void_t*)(gb + t + 64 * i),
                                         (lds_void_t*)(&ldsB[i * 64]), 16, 0, 0);

    __syncthreads();   // drains vmcnt(0): all 18 DMAs landed

    // Transpose-read own chain (bank-uniform b128), FK A.
    float tax, tay, taz;
    {
        const float4 r0 = ldsA[t * 9 + 0], r1 = ldsA[t * 9 + 1], r2 = ldsA[t * 9 + 2],
                     r3 = ldsA[t * 9 + 3], r4 = ldsA[t * 9 + 4], r5 = ldsA[t * 9 + 5],
                     r6 = ldsA[t * 9 + 6], r7 = ldsA[t * 9 + 7], r8 = ldsA[t * 9 + 8];
        chain_translation_q(r0, r1, r2, r3, r4, r5, r6, r7, r8, tax, tay, taz);
    }
    // FK B (separate buffer: no barrier needed).
    float tgx, tgy, tgz;
    {
        const float4 r0 = ldsB[t * 9 + 0], r1 = ldsB[t * 9 + 1], r2 = ldsB[t * 9 + 2],
                     r3 = ldsB[t * 9 + 3], r4 = ldsB[t * 9 + 4], r5 = ldsB[t * 9 + 5],
                     r6 = ldsB[t * 9 + 6], r7 = ldsB[t * 9 + 7], r8 = ldsB[t * 9 + 8];
        chain_translation_q(r0, r1, r2, r3, r4, r5, r6, r7, r8, tgx, tgy, tgz);
    }

    const float d0 = tax - tgx, d1 = tay - tgy, d2 = taz - tgz;
    float acc = d0 * d0 + d1 * d1 + d2 * d2;

    // single-wave reduction
#pragma unroll
    for (int off = 32; off > 0; off >>= 1)
        acc += __shfl_down(acc, off, 64);
    if (t == 0) partials[blockIdx.x] = acc;
}

__global__ __launch_bounds__(512) void reduce_kernel(const float* __restrict__ partials,
                                                     float* __restrict__ out) {
    const int t = threadIdx.x;
    const float4* __restrict__ p4 = reinterpret_cast<const float4*>(partials); // 2048 float4
    float s = 0.0f;
#pragma unroll
    for (int i = 0; i < 4; ++i) {
        const float4 v = p4[t + 512 * i];
        s += v.x + v.y + v.z + v.w;
    }
#pragma unroll
    for (int off = 32; off > 0; off >>= 1)
        s += __shfl_down(s, off, 64);
    __shared__ float smem[8];
    const int lane = t & 63, wid = t >> 6;
    if (lane == 0) smem[wid] = s;
    __syncthreads();
    if (t == 0) {
        float tot = 0.0f;
#pragma unroll
        for (int w = 0; w < 8; ++w) tot += smem[w];
        const float mean = tot / (262144.0f * 6.0f);
        out[0] = mean;  // pos_loss
        out[1] = mean;  // vel_loss == pos_loss (gt_prev cancels algebraically)
    }
}

extern "C" void kernel_launch(void* const* d_in, const int* in_sizes, int n_in,
                              void* d_out, int out_size, void* d_ws, size_t ws_size,
                              hipStream_t stream) {
    const float* output_pose = (const float*)d_in[0];
    const float* gt_pose     = (const float*)d_in[1];
    // d_in[2] (gt_prev_pose) cancels algebraically: vel_loss == pos_loss.
    float* out = (float*)d_out;
    float* partials = (float*)d_ws;   // 8192 floats = 32 KB

    fk_loss_kernel<<<NBLK, BLOCK, 0, stream>>>(output_pose, gt_pose, partials);
    reduce_kernel<<<1, 512, 0, stream>>>(partials, out);
}